// Round 3
// baseline (176.670 us; speedup 1.0000x reference)
//
#include <hip/hip_runtime.h>
#include <stdint.h>

#define ALPHA 1.702f
#define LIMIT 7.0f

typedef float f32x4 __attribute__((ext_vector_type(4)));
typedef __bf16 bf16x8 __attribute__((ext_vector_type(8)));

static __device__ __forceinline__ unsigned short f2bf(float f) {
    union { float f; uint32_t u; } v; v.f = f;
    uint32_t u = v.u;
    return (unsigned short)((u + 0x7FFFu + ((u >> 16) & 1u)) >> 16);
}
static __device__ __forceinline__ int imin(int a, int b) { return a < b ? a : b; }

#define GLL16(GP, LP) __builtin_amdgcn_global_load_lds( \
    (const __attribute__((address_space(1))) void*)(GP), \
    (__attribute__((address_space(3))) void*)(LP), 16, 0, 0)

// Swizzled LDS 16B-unit index for (tile-row, k-chunk-of-8). Staging writes
// unit u=tid holding (row=u>>2, kc=(u&3)^((u>>3)&3)); this is its inverse.
// Makes quarter-wave ds_read_b128 frag reads hit all 8 bank quartets.
static __device__ __forceinline__ int lsw(int row, int kc) {
    return row * 4 + (kc ^ ((row >> 1) & 3));
}

// Decode work ticket -> (expert, m-tile of 64 rows, col-tile of 128)
static __device__ __forceinline__ bool decode_tile(const int* __restrict__ cnt,
                                                   int w, int& e, int& tm, int& tn) {
    int cum = 0;
    #pragma unroll
    for (int ee = 0; ee < 8; ++ee) {
        const int nt = ((cnt[ee] + 63) >> 6) * 4;
        if (w < cum + nt) { const int loc = w - cum; e = ee; tm = loc >> 2; tn = loc & 3; return true; }
        cum += nt;
    }
    return false;
}

// ---------------------------------------------------------------------------
// prep: blocks [0,128): gate (RMSNorm + bf16 t + fp32 logits + top4 + routing
//       lists + aux partials + out init). blocks [128,6272): weight convert
//       fp32->bf16 with W1 glu/lin row split.
// ---------------------------------------------------------------------------
__global__ __launch_bounds__(256) void prep_kernel(
    const float* __restrict__ w1, const float* __restrict__ w2,
    unsigned short* __restrict__ w1p, unsigned short* __restrict__ w2b,
    const float* __restrict__ x,
    const float* __restrict__ norm_scale,
    const float* __restrict__ gate_w,
    const float* __restrict__ gate_b,
    const float* __restrict__ b2,
    unsigned short* __restrict__ t_bf,
    int* __restrict__ idx,        // [8][2048] compact token ids
    float* __restrict__ wcoef,    // [8][2048] combine weights per slot
    float* __restrict__ accum,    // [48] aux partials
    int* __restrict__ cnt,        // [8] per-expert counts
    float* __restrict__ out)
{
    __shared__ float red[4][48];
    __shared__ int   ltok[8][16];
    __shared__ float lwt[8][16];
    __shared__ int   lcnt[8];
    __shared__ int   gbase[8];

    if (blockIdx.x >= 128) {
        const int i4 = (blockIdx.x - 128) * 256 + threadIdx.x;
        const int n1 = 1048576;  // 8*1024*512/4 float4s of w1
        if (i4 < n1) {
            const int e = i4 >> 17;
            const int rem = i4 & 131071;
            const int r = rem >> 7;
            const int c = rem & 127;
            const int src = (r < 512) ? (2 * r) : (2 * (r - 512) + 1);
            float4 v = ((const float4*)w1)[(e << 17) + (src << 7) + c];
            ushort4 o = { f2bf(v.x), f2bf(v.y), f2bf(v.z), f2bf(v.w) };
            ((ushort4*)w1p)[i4] = o;
        } else {
            const int i2 = i4 - n1;
            float4 v = ((const float4*)w2)[i2];
            ushort4 o = { f2bf(v.x), f2bf(v.y), f2bf(v.z), f2bf(v.w) };
            ((ushort4*)w2b)[i2] = o;
        }
        return;
    }
    // ---- gate: 128 blocks, each wave handles 4 tokens serially ----
    if (threadIdx.x < 8) lcnt[threadIdx.x] = 0;
    __syncthreads();
    const int wave = threadIdx.x >> 6;
    const int lane = threadIdx.x & 63;

    float accP[8], accI[8], accC[32];
    #pragma unroll
    for (int e = 0; e < 8; ++e) { accP[e] = 0.f; accI[e] = 0.f; }
    #pragma unroll
    for (int i = 0; i < 32; ++i) accC[i] = 0.f;

    #pragma unroll
    for (int it = 0; it < 4; ++it) {
        const int t = blockIdx.x * 16 + wave * 4 + it;
        const float4* xr = (const float4*)(x + t * 512);
        float4 x0 = xr[lane * 2];
        float4 x1 = xr[lane * 2 + 1];
        float ss = x0.x*x0.x + x0.y*x0.y + x0.z*x0.z + x0.w*x0.w
                 + x1.x*x1.x + x1.y*x1.y + x1.z*x1.z + x1.w*x1.w;
        #pragma unroll
        for (int off = 32; off > 0; off >>= 1) ss += __shfl_xor(ss, off, 64);
        const float rstd = rsqrtf(ss * (1.f / 512.f) + 1e-6f);
        const float4* sr = (const float4*)norm_scale;
        float4 s0 = sr[lane * 2], s1 = sr[lane * 2 + 1];
        float tv[8];
        tv[0] = x0.x * rstd * s0.x; tv[1] = x0.y * rstd * s0.y;
        tv[2] = x0.z * rstd * s0.z; tv[3] = x0.w * rstd * s0.w;
        tv[4] = x1.x * rstd * s1.x; tv[5] = x1.y * rstd * s1.y;
        tv[6] = x1.z * rstd * s1.z; tv[7] = x1.w * rstd * s1.w;
        uint32_t p0 = (uint32_t)f2bf(tv[0]) | ((uint32_t)f2bf(tv[1]) << 16);
        uint32_t p1 = (uint32_t)f2bf(tv[2]) | ((uint32_t)f2bf(tv[3]) << 16);
        uint32_t p2 = (uint32_t)f2bf(tv[4]) | ((uint32_t)f2bf(tv[5]) << 16);
        uint32_t p3 = (uint32_t)f2bf(tv[6]) | ((uint32_t)f2bf(tv[7]) << 16);
        uint4 pk; pk.x = p0; pk.y = p1; pk.z = p2; pk.w = p3;
        ((uint4*)(t_bf + t * 512))[lane] = pk;
        float le[8];
        #pragma unroll
        for (int e = 0; e < 8; ++e) {
            const float4* gw = (const float4*)(gate_w + e * 512);
            float4 g0 = gw[lane * 2], g1 = gw[lane * 2 + 1];
            float d = tv[0]*g0.x + tv[1]*g0.y + tv[2]*g0.z + tv[3]*g0.w
                    + tv[4]*g1.x + tv[5]*g1.y + tv[6]*g1.z + tv[7]*g1.w;
            #pragma unroll
            for (int off = 32; off > 0; off >>= 1) d += __shfl_xor(d, off, 64);
            le[e] = d + gate_b[e];
        }
        float mx = le[0];
        #pragma unroll
        for (int e = 1; e < 8; ++e) mx = fmaxf(mx, le[e]);
        float pe[8], se = 0.f;
        #pragma unroll
        for (int e = 0; e < 8; ++e) { pe[e] = __expf(le[e] - mx); se += pe[e]; }
        const float sinv = 1.f / se;
        #pragma unroll
        for (int e = 0; e < 8; ++e) pe[e] *= sinv;
        unsigned picked = 0;
        int ik[4]; float wk[4];
        #pragma unroll
        for (int k = 0; k < 4; ++k) {
            float bv = -1.f; int bi = 0;
            #pragma unroll
            for (int e = 0; e < 8; ++e)
                if (!(picked & (1u << e)) && pe[e] > bv) { bv = pe[e]; bi = e; }
            ik[k] = bi; wk[k] = bv; picked |= (1u << bi);
        }
        const float winv = 1.f / (wk[0] + wk[1] + wk[2] + wk[3]);
        float nw[4];
        #pragma unroll
        for (int k = 0; k < 4; ++k) nw[k] = wk[k] * winv;
        float ce[8];
        #pragma unroll
        for (int e = 0; e < 8; ++e) {
            float c = 0.f;
            #pragma unroll
            for (int k = 0; k < 4; ++k) c += (ik[k] == e) ? nw[k] : 0.f;
            ce[e] = c;
        }
        if (lane == 0) {
            #pragma unroll
            for (int k = 0; k < 4; ++k) {
                const int e = ik[k];
                const int pos = atomicAdd(&lcnt[e], 1);
                ltok[e][pos] = t; lwt[e][pos] = nw[k];
            }
        }
        #pragma unroll
        for (int e = 0; e < 8; ++e) { accP[e] += pe[e]; accI[e] += le[e]; }
        #pragma unroll
        for (int k = 0; k < 4; ++k)
            #pragma unroll
            for (int e = 0; e < 8; ++e)
                accC[k * 8 + e] += (ik[k] == e) ? 1.f : 0.f;
        float ov[8];
        ov[0] = x0.x; ov[1] = x0.y; ov[2] = x0.z; ov[3] = x0.w;
        ov[4] = x1.x; ov[5] = x1.y; ov[6] = x1.z; ov[7] = x1.w;
        #pragma unroll
        for (int e = 0; e < 8; ++e) {
            const float4* br = (const float4*)(b2 + e * 512);
            float4 b0 = br[lane * 2], bb1 = br[lane * 2 + 1];
            ov[0] += ce[e] * b0.x; ov[1] += ce[e] * b0.y;
            ov[2] += ce[e] * b0.z; ov[3] += ce[e] * b0.w;
            ov[4] += ce[e] * bb1.x; ov[5] += ce[e] * bb1.y;
            ov[6] += ce[e] * bb1.z; ov[7] += ce[e] * bb1.w;
        }
        float4 o0, o1;
        o0.x = ov[0]; o0.y = ov[1]; o0.z = ov[2]; o0.w = ov[3];
        o1.x = ov[4]; o1.y = ov[5]; o1.z = ov[6]; o1.w = ov[7];
        float4* orow = (float4*)(out + t * 512);
        orow[lane * 2] = o0; orow[lane * 2 + 1] = o1;
    }
    if (lane == 0) {
        #pragma unroll
        for (int e = 0; e < 8; ++e) { red[wave][e] = accP[e]; red[wave][8 + e] = accI[e]; }
        #pragma unroll
        for (int i = 0; i < 32; ++i) red[wave][16 + i] = accC[i];
    }
    __syncthreads();
    if (threadIdx.x < 8)
        gbase[threadIdx.x] = atomicAdd(&cnt[threadIdx.x], lcnt[threadIdx.x]);
    __syncthreads();
    if (threadIdx.x < 128) {
        const int e = threadIdx.x >> 4, i = threadIdx.x & 15;
        if (i < lcnt[e]) {
            const int g = gbase[e] + i;
            idx[e * 2048 + g] = ltok[e][i];
            wcoef[e * 2048 + g] = lwt[e][i];
        }
    }
    if (threadIdx.x < 48) {
        float s = red[0][threadIdx.x] + red[1][threadIdx.x]
                + red[2][threadIdx.x] + red[3][threadIdx.x];
        atomicAdd(accum + threadIdx.x, s);
    }
}

// ---------------------------------------------------------------------------
// GEMM1 (routed) + swiglu*coeff epilogue, ticket-queue over 64x128 tiles.
// Block 512 computes the aux loss.
// ---------------------------------------------------------------------------
__global__ __launch_bounds__(256) void gemm1_swiglu(
    const unsigned short* __restrict__ A,    // t_bf [2048][512]
    const unsigned short* __restrict__ w1p,  // [8][1024][512] glu/lin split
    const float* __restrict__ b1,            // [8][1024] interleaved
    const int* __restrict__ idx,
    const float* __restrict__ wcoef,
    const int* __restrict__ cnt,
    int* __restrict__ tick,
    unsigned short* __restrict__ As,         // [8][2048][512] compact
    const float* __restrict__ accum,
    float* __restrict__ aux_out)
{
    if (blockIdx.x == 512) {
        if (threadIdx.x == 0) {
            float imp[8];
            float sl = 0.f;
            #pragma unroll
            for (int e = 0; e < 8; ++e) {
                float P = accum[e] * (1.f / 2048.f);
                imp[e] = accum[8 + e];
                float D = (16.f * accum[16 + e] + 8.f * accum[24 + e]
                         + 4.f * accum[32 + e] + 2.f * accum[40 + e]) * (1.f / 8192.f);
                sl += P * D;
            }
            float loss_load = 0.01f * 8.f * sl;
            float mean = 0.f;
            #pragma unroll
            for (int e = 0; e < 8; ++e) mean += imp[e];
            mean *= 0.125f;
            float var = 0.f;
            #pragma unroll
            for (int e = 0; e < 8; ++e) { float d = imp[e] - mean; var += d * d; }
            var *= (1.f / 7.f);
            float cv = sqrtf(var) / (mean + 1e-6f);
            *aux_out = loss_load + 0.01f * cv * cv;
        }
        return;
    }
    __shared__ unsigned short tA[64 * 32];
    __shared__ unsigned short tBg[128 * 32];
    __shared__ unsigned short tBl[128 * 32];
    __shared__ int s_w;
    const int tid = threadIdx.x;
    const int lane = tid & 63, wave = tid >> 6;
    const int quad = lane >> 4, l16 = lane & 15;
    const int srow = tid >> 2;
    const int skc  = (tid & 3) ^ ((tid >> 3) & 3);
    const int soff = skc * 8;

    for (;;) {
        if (tid == 0) s_w = atomicAdd(tick, 1);
        __syncthreads();
        const int w = s_w;
        int e, tm, tn;
        if (!decode_tile(cnt, w, e, tm, tn)) break;
        const int cnte = cnt[e];
        const int m0 = tm * 64, np = tn * 128;
        const int tok = idx[e * 2048 + imin(m0 + srow, cnte - 1)];
        const unsigned short* Bg = w1p + (e * 1024 + np) * 512;
        const unsigned short* Bl = Bg + 512 * 512;

        f32x4 accG[4][2], accL[4][2];
        #pragma unroll
        for (int i = 0; i < 4; ++i)
            #pragma unroll
            for (int j = 0; j < 2; ++j) {
                f32x4 z = {0.f, 0.f, 0.f, 0.f};
                accG[i][j] = z; accL[i][j] = z;
            }

        for (int k0 = 0; k0 < 512; k0 += 32) {
            GLL16(A + tok * 512 + k0 + soff, tA + tid * 8);
            GLL16(Bg + srow * 512 + k0 + soff,        tBg + tid * 8);
            GLL16(Bg + (64 + srow) * 512 + k0 + soff, tBg + (tid + 256) * 8);
            GLL16(Bl + srow * 512 + k0 + soff,        tBl + tid * 8);
            GLL16(Bl + (64 + srow) * 512 + k0 + soff, tBl + (tid + 256) * 8);
            __syncthreads();
            bf16x8 af[4], bg[2], bl[2];
            #pragma unroll
            for (int i = 0; i < 4; ++i)
                af[i] = *(const bf16x8*)(tA + lsw(i * 16 + l16, quad) * 8);
            #pragma unroll
            for (int j = 0; j < 2; ++j) {
                const int c = wave * 32 + j * 16 + l16;
                bg[j] = *(const bf16x8*)(tBg + lsw(c, quad) * 8);
                bl[j] = *(const bf16x8*)(tBl + lsw(c, quad) * 8);
            }
            #pragma unroll
            for (int i = 0; i < 4; ++i)
                #pragma unroll
                for (int j = 0; j < 2; ++j) {
                    accG[i][j] = __builtin_amdgcn_mfma_f32_16x16x32_bf16(af[i], bg[j], accG[i][j], 0, 0, 0);
                    accL[i][j] = __builtin_amdgcn_mfma_f32_16x16x32_bf16(af[i], bl[j], accL[i][j], 0, 0, 0);
                }
            __syncthreads();
        }

        #pragma unroll
        for (int j = 0; j < 2; ++j) {
            const int colp = np + wave * 32 + j * 16 + l16;   // [0,512)
            const float bgv = b1[e * 1024 + 2 * colp];
            const float blv = b1[e * 1024 + 2 * colp + 1];
            #pragma unroll
            for (int i = 0; i < 4; ++i) {
                const int sb = m0 + i * 16 + quad * 4;
                #pragma unroll
                for (int r = 0; r < 4; ++r) {
                    const int s = sb + r;
                    if (s < cnte) {
                        float g = fminf(fmaxf(accG[i][j][r] + bgv, -LIMIT), LIMIT);
                        float l = fminf(fmaxf(accL[i][j][r] + blv, -LIMIT), LIMIT);
                        float a = g / (1.f + __expf(-ALPHA * g)) + l + 1.f;
                        As[e * 1048576 + s * 512 + colp] = f2bf(a * wcoef[e * 2048 + s]);
                    }
                }
            }
        }
    }
}

// ---------------------------------------------------------------------------
// GEMM2 (routed): per-expert K=512, 64x128 tiles via ticket queue, scatter
// fp32 atomicAdd into pre-initialized out.
// ---------------------------------------------------------------------------
__global__ __launch_bounds__(256) void gemm2(
    const unsigned short* __restrict__ As,   // [8][2048][512] compact
    const unsigned short* __restrict__ w2b,  // [8][512][512]
    const int* __restrict__ idx,
    const int* __restrict__ cnt,
    int* __restrict__ tick,
    float* __restrict__ out)
{
    __shared__ unsigned short tA[64 * 32];
    __shared__ unsigned short tB[128 * 32];
    __shared__ int s_w;
    const int tid = threadIdx.x;
    const int lane = tid & 63, wave = tid >> 6;
    const int quad = lane >> 4, l16 = lane & 15;
    const int srow = tid >> 2;
    const int skc  = (tid & 3) ^ ((tid >> 3) & 3);
    const int soff = skc * 8;

    for (;;) {
        if (tid == 0) s_w = atomicAdd(tick, 1);
        __syncthreads();
        const int w = s_w;
        int e, tm, tn;
        if (!decode_tile(cnt, w, e, tm, tn)) break;
        const int cnte = cnt[e];
        const int m0 = tm * 64, n0 = tn * 128;
        const unsigned short* Asl = As + e * 1048576;
        const unsigned short* Bb  = w2b + e * 262144;

        f32x4 acc[4][2];
        #pragma unroll
        for (int i = 0; i < 4; ++i)
            #pragma unroll
            for (int j = 0; j < 2; ++j) { f32x4 z = {0.f, 0.f, 0.f, 0.f}; acc[i][j] = z; }

        for (int k0 = 0; k0 < 512; k0 += 32) {
            GLL16(Asl + (m0 + srow) * 512 + k0 + soff, tA + tid * 8);
            GLL16(Bb + (n0 + srow) * 512 + k0 + soff,      tB + tid * 8);
            GLL16(Bb + (n0 + 64 + srow) * 512 + k0 + soff, tB + (tid + 256) * 8);
            __syncthreads();
            bf16x8 af[4], bf[2];
            #pragma unroll
            for (int i = 0; i < 4; ++i)
                af[i] = *(const bf16x8*)(tA + lsw(i * 16 + l16, quad) * 8);
            #pragma unroll
            for (int j = 0; j < 2; ++j)
                bf[j] = *(const bf16x8*)(tB + lsw(wave * 32 + j * 16 + l16, quad) * 8);
            #pragma unroll
            for (int i = 0; i < 4; ++i)
                #pragma unroll
                for (int j = 0; j < 2; ++j)
                    acc[i][j] = __builtin_amdgcn_mfma_f32_16x16x32_bf16(af[i], bf[j], acc[i][j], 0, 0, 0);
            __syncthreads();
        }

        #pragma unroll
        for (int i = 0; i < 4; ++i) {
            const int sb = m0 + i * 16 + quad * 4;
            #pragma unroll
            for (int r = 0; r < 4; ++r) {
                const int s = sb + r;
                if (s < cnte) {
                    const int tok = idx[e * 2048 + s];
                    #pragma unroll
                    for (int j = 0; j < 2; ++j) {
                        const int col = n0 + wave * 32 + j * 16 + l16;
                        atomicAdd(&out[tok * 512 + col], acc[i][j][r]);
                    }
                }
            }
        }
    }
}

// ---------------------------------------------------------------------------
extern "C" void kernel_launch(void* const* d_in, const int* in_sizes, int n_in,
                              void* d_out, int out_size, void* d_ws, size_t ws_size,
                              hipStream_t stream)
{
    (void)in_sizes; (void)n_in; (void)out_size; (void)ws_size;
    const float* x          = (const float*)d_in[0];
    const float* norm_scale = (const float*)d_in[1];
    const float* gate_w     = (const float*)d_in[2];
    const float* gate_b     = (const float*)d_in[3];
    const float* mlp1_w     = (const float*)d_in[4];
    const float* mlp1_b     = (const float*)d_in[5];
    const float* mlp2_w     = (const float*)d_in[6];
    const float* mlp2_b     = (const float*)d_in[7];
    float* out = (float*)d_out;

    char* ws = (char*)d_ws;
    unsigned short* w1p   = (unsigned short*)(ws);              // 8,388,608 B
    unsigned short* w2b   = (unsigned short*)(ws + 8388608);    // 4,194,304 B
    unsigned short* tbf   = (unsigned short*)(ws + 12582912);   // 2,097,152 B
    unsigned short* As    = (unsigned short*)(ws + 14680064);   // 16,777,216 B
    int*            idx   = (int*)(ws + 31457280);              // 65,536 B
    float*          wcoef = (float*)(ws + 31522816);            // 65,536 B
    float*          accum = (float*)(ws + 31588352);            // 256 B
    int*            cnt   = (int*)(accum + 48);
    int*            tick  = cnt + 8;                            // [0]=g1 [1]=g2

    hipMemsetAsync(accum, 0, 256, stream);
    prep_kernel<<<6272, 256, 0, stream>>>(mlp1_w, mlp2_w, w1p, w2b,
                                          x, norm_scale, gate_w, gate_b, mlp2_b,
                                          tbf, idx, wcoef, accum, cnt, out);
    gemm1_swiglu<<<513, 256, 0, stream>>>(tbf, w1p, mlp1_b, idx, wcoef, cnt,
                                          tick, As, accum, out + 2048 * 512);
    gemm2<<<512, 256, 0, stream>>>(As, w2b, idx, cnt, tick + 1, out);
}

// Round 4
// 166.773 us; speedup vs baseline: 1.0593x; 1.0593x over previous
//
#include <hip/hip_runtime.h>
#include <stdint.h>

#define ALPHA 1.702f
#define LIMIT 7.0f

typedef float f32x4 __attribute__((ext_vector_type(4)));
typedef __bf16 bf16x8 __attribute__((ext_vector_type(8)));

static __device__ __forceinline__ unsigned short f2bf(float f) {
    union { float f; uint32_t u; } v; v.f = f;
    uint32_t u = v.u;
    return (unsigned short)((u + 0x7FFFu + ((u >> 16) & 1u)) >> 16);
}

#define GLL16(GP, LP) __builtin_amdgcn_global_load_lds( \
    (const __attribute__((address_space(1))) void*)(GP), \
    (__attribute__((address_space(3))) void*)(LP), 16, 0, 0)

// Conflict-free LDS swizzle (R3-verified: SQ_LDS_BANK_CONFLICT = 0).
// Staging unit u holds (row=u>>2, kc=(u&3)^((u>>3)&3)); lsw() is the inverse.
static __device__ __forceinline__ int lsw(int row, int kc) {
    return row * 4 + (kc ^ ((row >> 1) & 3));
}

// ---------------------------------------------------------------------------
// prep: blocks [0,6144): fp32->bf16 convert (W1 permuted glu/lin halves).
//       blocks [6144,6400): gate + RMSNorm + coeff + aux partials + out init.
// ---------------------------------------------------------------------------
__global__ __launch_bounds__(256) void prep_kernel(
    const float* __restrict__ w1, const float* __restrict__ w2,
    unsigned short* __restrict__ w1p, unsigned short* __restrict__ w2b,
    const float* __restrict__ x,
    const float* __restrict__ norm_scale,
    const float* __restrict__ gate_w,
    const float* __restrict__ gate_b,
    const float* __restrict__ b2,
    unsigned short* __restrict__ t_bf,
    float* __restrict__ coeff,
    float* __restrict__ accum,
    float* __restrict__ out)
{
    __shared__ float red[4][48];
    if (blockIdx.x < 6144) {
        const int idx = blockIdx.x * 256 + threadIdx.x;
        const int n1 = 1048576;
        if (idx < n1) {
            const int e = idx >> 17;
            const int rem = idx & 131071;
            const int r = rem >> 7;
            const int c = rem & 127;
            const int src = (r < 512) ? (2 * r) : (2 * (r - 512) + 1);
            float4 v = ((const float4*)w1)[(e << 17) + (src << 7) + c];
            ushort4 o = { f2bf(v.x), f2bf(v.y), f2bf(v.z), f2bf(v.w) };
            ((ushort4*)w1p)[idx] = o;
        } else {
            const int i2 = idx - n1;
            float4 v = ((const float4*)w2)[i2];
            ushort4 o = { f2bf(v.x), f2bf(v.y), f2bf(v.z), f2bf(v.w) };
            ((ushort4*)w2b)[i2] = o;
        }
        return;
    }
    const int bid = blockIdx.x - 6144;
    const int wave = threadIdx.x >> 6;
    const int lane = threadIdx.x & 63;

    float accP[8], accI[8], accC[32];
    #pragma unroll
    for (int e = 0; e < 8; ++e) { accP[e] = 0.f; accI[e] = 0.f; }
    #pragma unroll
    for (int i = 0; i < 32; ++i) accC[i] = 0.f;

    #pragma unroll
    for (int it = 0; it < 2; ++it) {
        const int t = bid * 8 + wave * 2 + it;
        const float4* xr = (const float4*)(x + t * 512);
        float4 x0 = xr[lane * 2];
        float4 x1 = xr[lane * 2 + 1];
        float ss = x0.x*x0.x + x0.y*x0.y + x0.z*x0.z + x0.w*x0.w
                 + x1.x*x1.x + x1.y*x1.y + x1.z*x1.z + x1.w*x1.w;
        #pragma unroll
        for (int off = 32; off > 0; off >>= 1) ss += __shfl_xor(ss, off, 64);
        const float rstd = rsqrtf(ss * (1.f / 512.f) + 1e-6f);
        const float4* sr = (const float4*)norm_scale;
        float4 s0 = sr[lane * 2], s1 = sr[lane * 2 + 1];
        float tv[8];
        tv[0] = x0.x * rstd * s0.x; tv[1] = x0.y * rstd * s0.y;
        tv[2] = x0.z * rstd * s0.z; tv[3] = x0.w * rstd * s0.w;
        tv[4] = x1.x * rstd * s1.x; tv[5] = x1.y * rstd * s1.y;
        tv[6] = x1.z * rstd * s1.z; tv[7] = x1.w * rstd * s1.w;
        uint32_t p0 = (uint32_t)f2bf(tv[0]) | ((uint32_t)f2bf(tv[1]) << 16);
        uint32_t p1 = (uint32_t)f2bf(tv[2]) | ((uint32_t)f2bf(tv[3]) << 16);
        uint32_t p2 = (uint32_t)f2bf(tv[4]) | ((uint32_t)f2bf(tv[5]) << 16);
        uint32_t p3 = (uint32_t)f2bf(tv[6]) | ((uint32_t)f2bf(tv[7]) << 16);
        uint4 pk; pk.x = p0; pk.y = p1; pk.z = p2; pk.w = p3;
        ((uint4*)(t_bf + t * 512))[lane] = pk;
        float le[8];
        #pragma unroll
        for (int e = 0; e < 8; ++e) {
            const float4* gw = (const float4*)(gate_w + e * 512);
            float4 g0 = gw[lane * 2], g1 = gw[lane * 2 + 1];
            float d = tv[0]*g0.x + tv[1]*g0.y + tv[2]*g0.z + tv[3]*g0.w
                    + tv[4]*g1.x + tv[5]*g1.y + tv[6]*g1.z + tv[7]*g1.w;
            #pragma unroll
            for (int off = 32; off > 0; off >>= 1) d += __shfl_xor(d, off, 64);
            le[e] = d + gate_b[e];
        }
        float mx = le[0];
        #pragma unroll
        for (int e = 1; e < 8; ++e) mx = fmaxf(mx, le[e]);
        float pe[8], se = 0.f;
        #pragma unroll
        for (int e = 0; e < 8; ++e) { pe[e] = __expf(le[e] - mx); se += pe[e]; }
        const float sinv = 1.f / se;
        #pragma unroll
        for (int e = 0; e < 8; ++e) pe[e] *= sinv;
        unsigned picked = 0;
        int ik[4]; float wk[4];
        #pragma unroll
        for (int k = 0; k < 4; ++k) {
            float bv = -1.f; int bi = 0;
            #pragma unroll
            for (int e = 0; e < 8; ++e)
                if (!(picked & (1u << e)) && pe[e] > bv) { bv = pe[e]; bi = e; }
            ik[k] = bi; wk[k] = bv; picked |= (1u << bi);
        }
        const float winv = 1.f / (wk[0] + wk[1] + wk[2] + wk[3]);
        float nw[4];
        #pragma unroll
        for (int k = 0; k < 4; ++k) nw[k] = wk[k] * winv;
        float ce[8];
        #pragma unroll
        for (int e = 0; e < 8; ++e) {
            float c = 0.f;
            #pragma unroll
            for (int k = 0; k < 4; ++k) c += (ik[k] == e) ? nw[k] : 0.f;
            ce[e] = c;
        }
        if (lane == 0) {
            #pragma unroll
            for (int e = 0; e < 8; ++e) coeff[t * 8 + e] = ce[e];
        }
        #pragma unroll
        for (int e = 0; e < 8; ++e) { accP[e] += pe[e]; accI[e] += le[e]; }
        #pragma unroll
        for (int k = 0; k < 4; ++k)
            #pragma unroll
            for (int e = 0; e < 8; ++e)
                accC[k * 8 + e] += (ik[k] == e) ? 1.f : 0.f;
        float ov[8];
        ov[0] = x0.x; ov[1] = x0.y; ov[2] = x0.z; ov[3] = x0.w;
        ov[4] = x1.x; ov[5] = x1.y; ov[6] = x1.z; ov[7] = x1.w;
        #pragma unroll
        for (int e = 0; e < 8; ++e) {
            const float4* br = (const float4*)(b2 + e * 512);
            float4 b0 = br[lane * 2], bb1 = br[lane * 2 + 1];
            ov[0] += ce[e] * b0.x; ov[1] += ce[e] * b0.y;
            ov[2] += ce[e] * b0.z; ov[3] += ce[e] * b0.w;
            ov[4] += ce[e] * bb1.x; ov[5] += ce[e] * bb1.y;
            ov[6] += ce[e] * bb1.z; ov[7] += ce[e] * bb1.w;
        }
        float4 o0, o1;
        o0.x = ov[0]; o0.y = ov[1]; o0.z = ov[2]; o0.w = ov[3];
        o1.x = ov[4]; o1.y = ov[5]; o1.z = ov[6]; o1.w = ov[7];
        float4* orow = (float4*)(out + t * 512);
        orow[lane * 2] = o0; orow[lane * 2 + 1] = o1;
    }
    if (lane == 0) {
        #pragma unroll
        for (int e = 0; e < 8; ++e) { red[wave][e] = accP[e]; red[wave][8 + e] = accI[e]; }
        #pragma unroll
        for (int i = 0; i < 32; ++i) red[wave][16 + i] = accC[i];
    }
    __syncthreads();
    if (threadIdx.x < 48) {
        float s = red[0][threadIdx.x] + red[1][threadIdx.x]
                + red[2][threadIdx.x] + red[3][threadIdx.x];
        atomicAdd(accum + threadIdx.x, s);
    }
}

// ---------------------------------------------------------------------------
// GEMM1 + swiglu*coeff, double-buffered pipelined K-loop (prefetch dist 2,
// raw s_barrier + fine-grained vmcnt — never vmcnt(0) mid-loop).
// grid 513: blocks 0..511 = 16 m-tiles x 32 col-tiles; block 512 = aux loss.
// ---------------------------------------------------------------------------
__global__ __launch_bounds__(256, 2) void gemm1_swiglu(
    const unsigned short* __restrict__ A,    // t_bf [2048][512]
    const unsigned short* __restrict__ w1p,  // [8][1024][512] glu/lin split
    const float* __restrict__ b1,            // [8][1024] interleaved
    const float* __restrict__ coeff,         // [2048][8]
    unsigned short* __restrict__ As,         // [2048][4096]
    const float* __restrict__ accum,
    float* __restrict__ aux_out)
{
    if (blockIdx.x == 512) {
        if (threadIdx.x == 0) {
            float imp[8], sl = 0.f;
            #pragma unroll
            for (int e = 0; e < 8; ++e) {
                float P = accum[e] * (1.f / 2048.f);
                imp[e] = accum[8 + e];
                float D = (16.f * accum[16 + e] + 8.f * accum[24 + e]
                         + 4.f * accum[32 + e] + 2.f * accum[40 + e]) * (1.f / 8192.f);
                sl += P * D;
            }
            float loss_load = 0.01f * 8.f * sl;
            float mean = 0.f;
            #pragma unroll
            for (int e = 0; e < 8; ++e) mean += imp[e];
            mean *= 0.125f;
            float var = 0.f;
            #pragma unroll
            for (int e = 0; e < 8; ++e) { float d = imp[e] - mean; var += d * d; }
            var *= (1.f / 7.f);
            float cv = sqrtf(var) / (mean + 1e-6f);
            *aux_out = loss_load + 0.01f * cv * cv;
        }
        return;
    }
    __shared__ unsigned short tA[2][4096];
    __shared__ unsigned short tBg[2][4096];
    __shared__ unsigned short tBl[2][4096];
    const int tid = threadIdx.x;
    const int bx = blockIdx.x;
    const int tile_p = bx & 31, tile_m = bx >> 5;
    const int e = tile_p >> 2;
    const int np = (tile_p & 3) * 128;
    const int m0 = tile_m * 128;
    const int lane = tid & 63, wave = tid >> 6;
    const int wm = (wave & 1) * 64, wn = (wave >> 1) * 64;
    const int quad = lane >> 4, l16 = lane & 15;
    const int srow = tid >> 2;
    const int soff = ((tid & 3) ^ ((tid >> 3) & 3)) * 8;

    const unsigned short* Ar0 = A + (m0 + srow) * 512 + soff;
    const unsigned short* Ar1 = A + (m0 + 64 + srow) * 512 + soff;
    const unsigned short* Bg = w1p + (e * 1024 + np) * 512;
    const unsigned short* Bg0 = Bg + srow * 512 + soff;
    const unsigned short* Bg1 = Bg + (64 + srow) * 512 + soff;
    const unsigned short* Bl0 = Bg0 + 512 * 512;
    const unsigned short* Bl1 = Bg1 + 512 * 512;

    int rA[4], rB[4];
    #pragma unroll
    for (int i = 0; i < 4; ++i) {
        rA[i] = lsw(wm + i * 16 + l16, quad) * 8;
        rB[i] = lsw(wn + i * 16 + l16, quad) * 8;
    }

    f32x4 accG[4][4], accL[4][4];
    #pragma unroll
    for (int i = 0; i < 4; ++i)
        #pragma unroll
        for (int j = 0; j < 4; ++j) {
            f32x4 z = {0.f, 0.f, 0.f, 0.f};
            accG[i][j] = z; accL[i][j] = z;
        }

#define STAGE1(s, k0) do { \
    GLL16(Ar0 + (k0), tA[s] + tid * 8); \
    GLL16(Ar1 + (k0), tA[s] + (tid + 256) * 8); \
    GLL16(Bg0 + (k0), tBg[s] + tid * 8); \
    GLL16(Bg1 + (k0), tBg[s] + (tid + 256) * 8); \
    GLL16(Bl0 + (k0), tBl[s] + tid * 8); \
    GLL16(Bl1 + (k0), tBl[s] + (tid + 256) * 8); \
} while (0)

    STAGE1(0, 0);
    STAGE1(1, 32);
    #pragma unroll
    for (int kt = 0; kt < 16; ++kt) {
        const int cur = kt & 1;
        if (kt < 15) asm volatile("s_waitcnt vmcnt(6)" ::: "memory");
        else         asm volatile("s_waitcnt vmcnt(0)" ::: "memory");
        asm volatile("s_barrier" ::: "memory");
        bf16x8 af[4], bg[4], bl[4];
        #pragma unroll
        for (int i = 0; i < 4; ++i) {
            af[i] = *(const bf16x8*)(tA[cur] + rA[i]);
            bg[i] = *(const bf16x8*)(tBg[cur] + rB[i]);
            bl[i] = *(const bf16x8*)(tBl[cur] + rB[i]);
        }
        asm volatile("s_waitcnt lgkmcnt(0)" ::: "memory");
        asm volatile("s_barrier" ::: "memory");
        if (kt < 14) STAGE1(cur, (kt + 2) * 32);
        #pragma unroll
        for (int i = 0; i < 4; ++i)
            #pragma unroll
            for (int j = 0; j < 4; ++j) {
                accG[i][j] = __builtin_amdgcn_mfma_f32_16x16x32_bf16(af[i], bg[j], accG[i][j], 0, 0, 0);
                accL[i][j] = __builtin_amdgcn_mfma_f32_16x16x32_bf16(af[i], bl[j], accL[i][j], 0, 0, 0);
            }
    }
#undef STAGE1

    float cw[4][4];
    #pragma unroll
    for (int i = 0; i < 4; ++i) {
        const int rowb = m0 + wm + i * 16 + quad * 4;
        #pragma unroll
        for (int r = 0; r < 4; ++r) cw[i][r] = coeff[(rowb + r) * 8 + e];
    }
    #pragma unroll
    for (int j = 0; j < 4; ++j) {
        const int colp = np + wn + j * 16 + l16;
        const float bgv = b1[e * 1024 + 2 * colp];
        const float blv = b1[e * 1024 + 2 * colp + 1];
        #pragma unroll
        for (int i = 0; i < 4; ++i) {
            const int rowb = m0 + wm + i * 16 + quad * 4;
            #pragma unroll
            for (int r = 0; r < 4; ++r) {
                float g = fminf(fmaxf(accG[i][j][r] + bgv, -LIMIT), LIMIT);
                float l = fminf(fmaxf(accL[i][j][r] + blv, -LIMIT), LIMIT);
                float a = g / (1.f + __expf(-ALPHA * g)) + l + 1.f;
                a *= cw[i][r];
                As[(rowb + r) * 4096 + e * 512 + colp] = f2bf(a);
            }
        }
    }
}

// ---------------------------------------------------------------------------
// GEMM2 split-K=8 (expert slices), same pipelined K-loop, fp32 atomicAdd.
// grid 512 = 4 n x 16 m x 8 sk.
// ---------------------------------------------------------------------------
__global__ __launch_bounds__(256, 2) void gemm2(
    const unsigned short* __restrict__ As,  // [2048][4096]
    const unsigned short* __restrict__ w2b, // [8][512][512]
    float* __restrict__ out)                // [2048][512]
{
    __shared__ unsigned short tA[2][4096];
    __shared__ unsigned short tB[2][4096];
    const int tid = threadIdx.x;
    const int bx = blockIdx.x;
    const int tile_n = bx & 3;
    const int tile_m = (bx >> 2) & 15;
    const int e = bx >> 6;
    const int m0 = tile_m * 128, n0 = tile_n * 128;
    const int lane = tid & 63, wave = tid >> 6;
    const int wm = (wave & 1) * 64, wn = (wave >> 1) * 64;
    const int quad = lane >> 4, l16 = lane & 15;
    const int srow = tid >> 2;
    const int soff = ((tid & 3) ^ ((tid >> 3) & 3)) * 8;

    const unsigned short* Ar0 = As + (m0 + srow) * 4096 + e * 512 + soff;
    const unsigned short* Ar1 = As + (m0 + 64 + srow) * 4096 + e * 512 + soff;
    const unsigned short* Bb  = w2b + e * 262144;
    const unsigned short* Br0 = Bb + (n0 + srow) * 512 + soff;
    const unsigned short* Br1 = Bb + (n0 + 64 + srow) * 512 + soff;

    int rA[4], rB[4];
    #pragma unroll
    for (int i = 0; i < 4; ++i) {
        rA[i] = lsw(wm + i * 16 + l16, quad) * 8;
        rB[i] = lsw(wn + i * 16 + l16, quad) * 8;
    }

    f32x4 acc[4][4];
    #pragma unroll
    for (int i = 0; i < 4; ++i)
        #pragma unroll
        for (int j = 0; j < 4; ++j) { f32x4 z = {0.f, 0.f, 0.f, 0.f}; acc[i][j] = z; }

#define STAGE2(s, k0) do { \
    GLL16(Ar0 + (k0), tA[s] + tid * 8); \
    GLL16(Ar1 + (k0), tA[s] + (tid + 256) * 8); \
    GLL16(Br0 + (k0), tB[s] + tid * 8); \
    GLL16(Br1 + (k0), tB[s] + (tid + 256) * 8); \
} while (0)

    STAGE2(0, 0);
    STAGE2(1, 32);
    #pragma unroll
    for (int kt = 0; kt < 16; ++kt) {
        const int cur = kt & 1;
        if (kt < 15) asm volatile("s_waitcnt vmcnt(4)" ::: "memory");
        else         asm volatile("s_waitcnt vmcnt(0)" ::: "memory");
        asm volatile("s_barrier" ::: "memory");
        bf16x8 af[4], bf[4];
        #pragma unroll
        for (int i = 0; i < 4; ++i) {
            af[i] = *(const bf16x8*)(tA[cur] + rA[i]);
            bf[i] = *(const bf16x8*)(tB[cur] + rB[i]);
        }
        asm volatile("s_waitcnt lgkmcnt(0)" ::: "memory");
        asm volatile("s_barrier" ::: "memory");
        if (kt < 14) STAGE2(cur, (kt + 2) * 32);
        #pragma unroll
        for (int i = 0; i < 4; ++i)
            #pragma unroll
            for (int j = 0; j < 4; ++j)
                acc[i][j] = __builtin_amdgcn_mfma_f32_16x16x32_bf16(af[i], bf[j], acc[i][j], 0, 0, 0);
    }
#undef STAGE2

    #pragma unroll
    for (int j = 0; j < 4; ++j) {
        const int col = n0 + wn + j * 16 + l16;
        #pragma unroll
        for (int i = 0; i < 4; ++i) {
            const int rowb = m0 + wm + i * 16 + quad * 4;
            #pragma unroll
            for (int r = 0; r < 4; ++r)
                atomicAdd(&out[(rowb + r) * 512 + col], acc[i][j][r]);
        }
    }
}

// ---------------------------------------------------------------------------
extern "C" void kernel_launch(void* const* d_in, const int* in_sizes, int n_in,
                              void* d_out, int out_size, void* d_ws, size_t ws_size,
                              hipStream_t stream)
{
    (void)in_sizes; (void)n_in; (void)out_size; (void)ws_size;
    const float* x          = (const float*)d_in[0];
    const float* norm_scale = (const float*)d_in[1];
    const float* gate_w     = (const float*)d_in[2];
    const float* gate_b     = (const float*)d_in[3];
    const float* mlp1_w     = (const float*)d_in[4];
    const float* mlp1_b     = (const float*)d_in[5];
    const float* mlp2_w     = (const float*)d_in[6];
    const float* mlp2_b     = (const float*)d_in[7];
    float* out = (float*)d_out;

    char* ws = (char*)d_ws;
    unsigned short* w1p   = (unsigned short*)(ws);              // 8,388,608 B
    unsigned short* w2b   = (unsigned short*)(ws + 8388608);    // 4,194,304 B
    unsigned short* tbf   = (unsigned short*)(ws + 12582912);   // 2,097,152 B
    unsigned short* As    = (unsigned short*)(ws + 14680064);   // 16,777,216 B
    float*          coeff = (float*)(ws + 31457280);            // 65,536 B
    float*          accum = (float*)(ws + 31522816);            // 192 B

    hipMemsetAsync(accum, 0, 192, stream);
    prep_kernel<<<6400, 256, 0, stream>>>(mlp1_w, mlp2_w, w1p, w2b,
                                          x, norm_scale, gate_w, gate_b, mlp2_b,
                                          tbf, coeff, accum, out);
    gemm1_swiglu<<<513, 256, 0, stream>>>(tbf, w1p, mlp1_b, coeff, As,
                                          accum, out + 2048 * 512);
    gemm2<<<512, 256, 0, stream>>>(As, w2b, out);
}